// Round 2
// baseline (1215.227 us; speedup 1.0000x reference)
//
#include <hip/hip_runtime.h>

// HeteroGAT: 2-layer bipartite GAT (heads=4,ch=25 concat + edge feat; then heads=1,ch=100).
// R6: layer-1 gather was HBM-bound (320us, 61% peak, ~470B/edge random reads).
//   -> layer-1 src tables packed bf16 [N][104] (100 h + 4 a_src), 208B/row.
//   -> dst-role gemms store NO H.
// R7 (resubmit; rounds 0-1 never acquired a GPU): layer-2 gather is the mirror image
//   (fp32 [Ns][100] rows, ~408B/edge random).
//   -> pack layer-2 src H as bf16 [N][100] (200B/row); a_src/a_dst stay fp32 so the
//      logit/exp path is untouched; only value rows are quantized (same as layer-1).
//   Predicted: gather1 FETCH ~halves, dur ~-40%; gemm2 WRITE_SIZE 40->20MB.

#define NNODES 50000
#define NEDGES 800000
#define SCAN_T 1024
#define SCAN_NBLK ((NNODES + SCAN_T - 1) / SCAN_T)  // 49

typedef unsigned short u16;
typedef unsigned int u32;

__device__ __forceinline__ float b2f(u16 u) {
    union { u32 i; float f; } x;
    x.i = ((u32)u) << 16;
    return x.f;
}
__device__ __forceinline__ u16 f2b(float f) {  // RN-even
    union { float f; u32 i; } x;
    x.f = f;
    u32 r = x.i + 0x7FFFu + ((x.i >> 16) & 1u);
    return (u16)(r >> 16);
}

// ---------------- ce[h] = sum_c We[h*25+c]*ae[h*25+c] (edge-attn constant) ----------------
__global__ void ce_kernel(const float* __restrict__ WeA, const float* __restrict__ aeA,
                          const float* __restrict__ WeB, const float* __restrict__ aeB,
                          float* __restrict__ ce /*[8]: 0..3=AB, 4..7=BA*/) {
    const float* We = blockIdx.x ? WeB : WeA;
    const float* ae = blockIdx.x ? aeB : aeA;
    __shared__ float s[4];
    int tid = threadIdx.x;
    if (tid < 4) s[tid] = 0.f;
    __syncthreads();
    if (tid < 100) atomicAdd(&s[tid / 25], We[tid] * ae[tid]);
    __syncthreads();
    if (tid < 4) ce[blockIdx.x * 4 + tid] = s[tid];
}

// ---------------- CSR build ----------------
__global__ void count_kernel(const int* __restrict__ eiA, const int* __restrict__ eiB,
                             int E, int* cntA, int* cntB) {
    int i = blockIdx.x * blockDim.x + threadIdx.x;
    if (i < E) atomicAdd(&cntA[eiA[E + i]], 1);
    else if (i < 2 * E) atomicAdd(&cntB[eiB[E + (i - E)]], 1);
}

__global__ __launch_bounds__(SCAN_T) void scanA_kernel(
    const int* __restrict__ cntA, const int* __restrict__ cntB,
    int* __restrict__ roA, int* __restrict__ roB, int* __restrict__ partial, int N) {
    const int dir = blockIdx.y;
    const int* cnt = dir ? cntB : cntA;
    int* ro = dir ? roB : roA;
    const int tid = threadIdx.x;
    const int i = blockIdx.x * SCAN_T + tid;
    __shared__ int sm[SCAN_T];
    sm[tid] = (i < N) ? cnt[i] : 0;
    __syncthreads();
    for (int off = 1; off < SCAN_T; off <<= 1) {
        int t = (tid >= off) ? sm[tid - off] : 0;
        __syncthreads();
        sm[tid] += t;
        __syncthreads();
    }
    if (i < N) ro[i + 1] = sm[tid];
    if (tid == SCAN_T - 1) partial[dir * 64 + blockIdx.x] = sm[tid];
}

__global__ void scanB_kernel(int* __restrict__ partial, int nblk) {
    __shared__ int sm[128];
    const int tid = threadIdx.x;
    sm[tid] = ((tid & 63) < nblk) ? partial[tid] : 0;
    __syncthreads();
    if (tid < 2) {
        int run = 0;
        for (int b = 0; b < nblk; ++b) {
            int t = sm[tid * 64 + b];
            sm[tid * 64 + b] = run;
            run += t;
        }
    }
    __syncthreads();
    partial[tid] = sm[tid];
}

__global__ __launch_bounds__(SCAN_T) void scanC_kernel(
    const int* __restrict__ cntA, const int* __restrict__ cntB,
    int* __restrict__ roA, int* __restrict__ roB,
    int* __restrict__ curA, int* __restrict__ curB,
    const int* __restrict__ partial, int N) {
    const int dir = blockIdx.y;
    const int* cnt = dir ? cntB : cntA;
    int* ro = dir ? roB : roA;
    int* cur = dir ? curB : curA;
    const int poff = partial[dir * 64 + blockIdx.x];
    const int i = blockIdx.x * SCAN_T + threadIdx.x;
    if (i < N) {
        int c = cnt[i];
        int r = ro[i + 1] + poff;
        ro[i + 1] = r;
        cur[i] = r - c;
        if (i == 0) ro[0] = 0;
    }
}

__global__ void fill_kernel(const int* __restrict__ eiA, const int* __restrict__ eiB,
                            const float* __restrict__ wA, const float* __restrict__ wB,
                            int E, int* curA, int* curB,
                            int* __restrict__ ssA, int* __restrict__ ssB,
                            float* __restrict__ swA, float* __restrict__ swB) {
    int i = blockIdx.x * blockDim.x + threadIdx.x;
    if (i < E) {
        int s = eiA[i], d = eiA[E + i];
        int pos = atomicAdd(&curA[d], 1);
        ssA[pos] = s; swA[pos] = wA[i];
    } else if (i < 2 * E) {
        int j = i - E;
        int s = eiB[j], d = eiB[E + j];
        int pos = atomicAdd(&curB[d], 1);
        ssB[pos] = s; swB[pos] = wB[j];
    }
}

// ---------------- GEMM [N,K]x[K,100] + fused att ----------------
// 128 nodes/block; lane owns nodes (lane, lane+64); wave w owns cols [25w,25w+25).
// Loop: W via uniform-address loads (s_load/lgkm), X via per-lane dwordx4 (vmcnt).
// HEADS==4 src role (H!=null): epilogue packs bf16 [node][104] (100 h + 4 a_src).
// HEADS==4 dst role (H==null): att[N,4] fp32 only.
// HEADS==1 src role: packed bf16 H [node][100] + att[N] fp32; dst role: att[N] only.
struct GemmArgs {
    const float* X;
    const float* W;
    const float* a;
    void* H;
    float* att;
};

template <int K, int HEADS>
__global__ __launch_bounds__(256, 4) void gemm_att_kernel(
    GemmArgs g0, GemmArgs g1, GemmArgs g2, GemmArgs g3, int N) {
    const GemmArgs ga[4] = {g0, g1, g2, g3};
    const GemmArgs g = ga[blockIdx.y];
    constexpr int SMEM_BYTES = (HEADS == 4) ? (64 * 106 * 2) : (64 * 102 * 2 + 4 * 128 * 4);
    __shared__ __align__(16) char smem[SMEM_BYTES];
    const int tid = threadIdx.x;
    const int lane = tid & 63;
    const int w = tid >> 6;
    const int node0 = blockIdx.x * 128;
    const int nA = node0 + lane;
    const int nB = node0 + 64 + lane;
    const bool vA = nA < N, vB = nB < N;
    const float* xr0 = g.X + (size_t)(vA ? nA : (N - 1)) * K;
    const float* xr1 = g.X + (size_t)(vB ? nB : (N - 1)) * K;

    const int c0 = 25 * w;  // wave-uniform
    const float* Wp = g.W + c0;

    float acc0[25], acc1[25];
#pragma unroll
    for (int j = 0; j < 25; ++j) { acc0[j] = 0.f; acc1[j] = 0.f; }

    float4 xq0 = *(const float4*)xr0;
    float4 xq1 = *(const float4*)xr1;

    for (int k0 = 0; k0 < K; k0 += 4) {
        const int knx = (k0 + 4 < K) ? (k0 + 4) : 0;
        const float4 xn0 = *(const float4*)(xr0 + knx);
        const float4 xn1 = *(const float4*)(xr1 + knx);
        const float xs0[4] = {xq0.x, xq0.y, xq0.z, xq0.w};
        const float xs1[4] = {xq1.x, xq1.y, xq1.z, xq1.w};
#pragma unroll
        for (int kk = 0; kk < 4; ++kk) {
            float wr[25];
#pragma unroll
            for (int j = 0; j < 25; ++j) wr[j] = Wp[(k0 + kk) * 100 + j];  // uniform -> s_load
#pragma unroll
            for (int j = 0; j < 25; ++j) {
                acc0[j] = fmaf(xs0[kk], wr[j], acc0[j]);
                acc1[j] = fmaf(xs1[kk], wr[j], acc1[j]);
            }
        }
        xq0 = xn0;
        xq1 = xn1;
    }

    float ap0 = 0.f, ap1 = 0.f;
#pragma unroll
    for (int j = 0; j < 25; ++j) {
        const float av = g.a[c0 + j];
        ap0 = fmaf(acc0[j], av, ap0);
        ap1 = fmaf(acc1[j], av, ap1);
    }

    const int rem = N - node0;
    if (HEADS == 4) {
        if (g.H == nullptr) {  // dst role: a_dst only
            if (vA) g.att[(size_t)nA * 4 + w] = ap0;
            if (vB) g.att[(size_t)nB * 4 + w] = ap1;
        } else {               // src role: packed bf16 rows [104], LDS stride 106 (odd uints)
            u16* sh = (u16*)smem;
            u32* sh32 = (u32*)smem;
            // chunk A
#pragma unroll
            for (int j = 0; j < 25; ++j) sh[lane * 106 + c0 + j] = f2b(acc0[j]);
            sh[lane * 106 + 100 + w] = f2b(ap0);
            __syncthreads();
            {
                const int limA = ((rem < 64) ? rem : 64) * 52;
                u32* Hb = (u32*)g.H + (size_t)node0 * 52;
                for (int i = tid; i < 64 * 52; i += 256) {
                    if (i < limA) {
                        int nd = i / 52;
                        Hb[i] = sh32[nd * 53 + (i - nd * 52)];
                    }
                }
            }
            __syncthreads();
            // chunk B
#pragma unroll
            for (int j = 0; j < 25; ++j) sh[lane * 106 + c0 + j] = f2b(acc1[j]);
            sh[lane * 106 + 100 + w] = f2b(ap1);
            __syncthreads();
            {
                const int remB = rem - 64;
                const int limB = ((remB < 64) ? (remB < 0 ? 0 : remB) : 64) * 52;
                u32* Hb = (u32*)g.H + (size_t)(node0 + 64) * 52;
                for (int i = tid; i < 64 * 52; i += 256) {
                    if (i < limB) {
                        int nd = i / 52;
                        Hb[i] = sh32[nd * 53 + (i - nd * 52)];
                    }
                }
            }
        }
    } else {
        // HEADS==1: packed bf16 rows [100] (50 u32), LDS stride 102 u16 (51 u32, odd)
        u16* sh = (u16*)smem;
        u32* sh32 = (u32*)smem;
        float* attp = (float*)(smem + 64 * 102 * 2);
        attp[w * 128 + lane] = ap0;
        attp[w * 128 + 64 + lane] = ap1;
        if (g.H != nullptr) {
            // chunk A
#pragma unroll
            for (int j = 0; j < 25; ++j) sh[lane * 102 + c0 + j] = f2b(acc0[j]);
            __syncthreads();
            {
                const int limA = ((rem < 64) ? rem : 64) * 50;
                u32* Hb = (u32*)g.H + (size_t)node0 * 50;
                for (int i = tid; i < 64 * 50; i += 256) {
                    if (i < limA) {
                        int nd = i / 50;
                        Hb[i] = sh32[nd * 51 + (i - nd * 50)];
                    }
                }
                if (tid < 128 && node0 + tid < N)
                    g.att[node0 + tid] =
                        attp[tid] + attp[128 + tid] + attp[256 + tid] + attp[384 + tid];
            }
            __syncthreads();
            // chunk B
#pragma unroll
            for (int j = 0; j < 25; ++j) sh[lane * 102 + c0 + j] = f2b(acc1[j]);
            __syncthreads();
            {
                const int remB = rem - 64;
                const int limB = ((remB < 64) ? (remB < 0 ? 0 : remB) : 64) * 50;
                u32* Hb = (u32*)g.H + (size_t)(node0 + 64) * 50;
                for (int i = tid; i < 64 * 50; i += 256) {
                    if (i < limB) {
                        int nd = i / 50;
                        Hb[i] = sh32[nd * 51 + (i - nd * 50)];
                    }
                }
            }
        } else {
            __syncthreads();
            if (tid < 128 && node0 + tid < N)
                g.att[node0 + tid] =
                    attp[tid] + attp[128 + tid] + attp[256 + tid] + attp[384 + tid];
        }
    }
}

// ---------------- layer-1 gather: wave per dst node, packed bf16 src rows ----------------
struct Gather4Args {
    const int* ro;
    const int* ss;
    const float* sw;
    const u16* hp;     // [Ns][104] bf16: 0..99 h, 100..103 a_src
    const float* ad;   // [Nd,4] fp32
    const float* ce;   // [4]
    const float* bias; // [100]
    float* outp;       // [Nd,100]
};

__global__ __launch_bounds__(256) void gather4_kernel(Gather4Args ga0, Gather4Args ga1, int Nd) {
    const Gather4Args ga[2] = {ga0, ga1};
    const Gather4Args g = ga[blockIdx.y];
    int wid = (int)((blockIdx.x * blockDim.x + threadIdx.x) >> 6);
    if (wid >= Nd) return;
    const int n = __builtin_amdgcn_readfirstlane(wid);
    const int lane = threadIdx.x & 63;
    const int beg = g.ro[n], end = g.ro[n + 1];
    const int c0 = lane, c1 = 64 + lane;
    const bool has1 = (c1 < 100);
    const int h0 = c0 / 25;
    const int h1 = (c1 / 25) & 3;
    const float ce0 = g.ce[h0], ce1 = g.ce[h1];
    const float ad0 = g.ad[n * 4 + h0], ad1 = g.ad[n * 4 + h1];
    float acc0 = 0.f, acc1 = 0.f, d0 = 0.f, d1 = 0.f;
    int p = beg;
    for (; p + 1 < end; p += 2) {
        const int sa = g.ss[p], sb = g.ss[p + 1];
        const float wa = g.sw[p], wb = g.sw[p + 1];
        const u16* ra = g.hp + (size_t)sa * 104;
        const u16* rb = g.hp + (size_t)sb * 104;
        float la0 = b2f(ra[100 + h0]) + ad0 + wa * ce0;
        float la1 = b2f(ra[100 + h1]) + ad1 + wa * ce1;
        float lb0 = b2f(rb[100 + h0]) + ad0 + wb * ce0;
        float lb1 = b2f(rb[100 + h1]) + ad1 + wb * ce1;
        la0 = fmaxf(la0, 0.2f * la0); la1 = fmaxf(la1, 0.2f * la1);
        lb0 = fmaxf(lb0, 0.2f * lb0); lb1 = fmaxf(lb1, 0.2f * lb1);
        const float pa0 = __expf(la0), pa1 = __expf(la1);
        const float pb0 = __expf(lb0), pb1 = __expf(lb1);
        const float va0 = b2f(ra[c0]), vb0 = b2f(rb[c0]);
        const float va1 = has1 ? b2f(ra[c1]) : 0.f;
        const float vb1 = has1 ? b2f(rb[c1]) : 0.f;
        acc0 = fmaf(pa0, va0, acc0); acc0 = fmaf(pb0, vb0, acc0);
        acc1 = fmaf(pa1, va1, acc1); acc1 = fmaf(pb1, vb1, acc1);
        d0 += pa0 + pb0;
        d1 += pa1 + pb1;
    }
    if (p < end) {
        const int s = g.ss[p];
        const float ww = g.sw[p];
        const u16* ra = g.hp + (size_t)s * 104;
        float l0 = b2f(ra[100 + h0]) + ad0 + ww * ce0;
        float l1 = b2f(ra[100 + h1]) + ad1 + ww * ce1;
        l0 = fmaxf(l0, 0.2f * l0);
        l1 = fmaxf(l1, 0.2f * l1);
        const float p0 = __expf(l0);
        const float p1 = __expf(l1);
        acc0 = fmaf(p0, b2f(ra[c0]), acc0);
        acc1 = fmaf(p1, has1 ? b2f(ra[c1]) : 0.f, acc1);
        d0 += p0;
        d1 += p1;
    }
    float r0 = (end > beg) ? acc0 / d0 : 0.f;
    float r1 = (end > beg) ? acc1 / d1 : 0.f;
    r0 += g.bias[c0];
    r0 = (r0 > 0.f) ? r0 : (__expf(r0) - 1.f);  // elu
    g.outp[(size_t)n * 100 + c0] = r0;
    if (has1) {
        r1 += g.bias[c1];
        r1 = (r1 > 0.f) ? r1 : (__expf(r1) - 1.f);
        g.outp[(size_t)n * 100 + c1] = r1;
    }
}

// ---------------- layer-2 gather: wave per dst node, heads=1, ch=100, bf16 rows ----------------
struct Gather1Args {
    const int* ro;
    const int* ss;
    const u16* hp;     // [Ns][100] bf16
    const float* as_;  // [Ns] fp32
    const float* ad;   // [Nd] fp32
    const float* bias; // [100]
    float* outp;       // [Nd,100]
};

__global__ __launch_bounds__(256) void gather1_kernel(Gather1Args ga0, Gather1Args ga1, int Nd) {
    const Gather1Args ga[2] = {ga0, ga1};
    const Gather1Args g = ga[blockIdx.y];
    int wid = (int)((blockIdx.x * blockDim.x + threadIdx.x) >> 6);
    if (wid >= Nd) return;
    const int n = __builtin_amdgcn_readfirstlane(wid);
    const int lane = threadIdx.x & 63;
    const int beg = g.ro[n], end = g.ro[n + 1];
    const int c0 = lane, c1 = 64 + lane;
    const bool has1 = (c1 < 100);
    const float adn = g.ad[n];
    float acc0 = 0.f, acc1 = 0.f, d0 = 0.f;
    int p = beg;
    for (; p + 1 < end; p += 2) {
        const int sa = g.ss[p], sb = g.ss[p + 1];
        float la = g.as_[sa] + adn;
        float lb = g.as_[sb] + adn;
        la = fmaxf(la, 0.2f * la);
        lb = fmaxf(lb, 0.2f * lb);
        const float pa = __expf(la), pb = __expf(lb);
        const u16* hra = g.hp + (size_t)sa * 100;
        const u16* hrb = g.hp + (size_t)sb * 100;
        const float va0 = b2f(hra[c0]), vb0 = b2f(hrb[c0]);
        const float va1 = has1 ? b2f(hra[c1]) : 0.f;
        const float vb1 = has1 ? b2f(hrb[c1]) : 0.f;
        acc0 = fmaf(pa, va0, acc0); acc0 = fmaf(pb, vb0, acc0);
        acc1 = fmaf(pa, va1, acc1); acc1 = fmaf(pb, vb1, acc1);
        d0 += pa + pb;
    }
    if (p < end) {
        const int s = g.ss[p];
        float l = g.as_[s] + adn;
        l = fmaxf(l, 0.2f * l);
        const float pe = __expf(l);
        const u16* hrow = g.hp + (size_t)s * 100;
        acc0 = fmaf(pe, b2f(hrow[c0]), acc0);
        acc1 = fmaf(pe, has1 ? b2f(hrow[c1]) : 0.f, acc1);
        d0 += pe;
    }
    float r0 = (end > beg) ? acc0 / d0 : 0.f;
    float r1 = (end > beg) ? acc1 / d0 : 0.f;
    g.outp[(size_t)n * 100 + c0] = r0 + g.bias[c0];
    if (has1) g.outp[(size_t)n * 100 + c1] = r1 + g.bias[c1];
}

extern "C" void kernel_launch(void* const* d_in, const int* in_sizes, int n_in,
                              void* d_out, int out_size, void* d_ws, size_t ws_size,
                              hipStream_t stream) {
    const float* x_A   = (const float*)d_in[0];
    const float* x_B   = (const float*)d_in[1];
    const int*   ei_AB = (const int*)d_in[2];
    const int*   ei_BA = (const int*)d_in[3];
    const float* w_AB  = (const float*)d_in[4];
    const float* w_BA  = (const float*)d_in[5];
    const float* l1AB_Ws = (const float*)d_in[6];
    const float* l1AB_Wd = (const float*)d_in[7];
    const float* l1AB_as = (const float*)d_in[8];
    const float* l1AB_ad = (const float*)d_in[9];
    const float* l1AB_We = (const float*)d_in[10];
    const float* l1AB_ae = (const float*)d_in[11];
    const float* l1AB_b  = (const float*)d_in[12];
    const float* l2AB_Ws = (const float*)d_in[13];
    const float* l2AB_Wd = (const float*)d_in[14];
    const float* l2AB_as = (const float*)d_in[15];
    const float* l2AB_ad = (const float*)d_in[16];
    const float* l2AB_b  = (const float*)d_in[17];
    const float* l1BA_Ws = (const float*)d_in[18];
    const float* l1BA_Wd = (const float*)d_in[19];
    const float* l1BA_as = (const float*)d_in[20];
    const float* l1BA_ad = (const float*)d_in[21];
    const float* l1BA_We = (const float*)d_in[22];
    const float* l1BA_ae = (const float*)d_in[23];
    const float* l1BA_b  = (const float*)d_in[24];
    const float* l2BA_Ws = (const float*)d_in[25];
    const float* l2BA_Wd = (const float*)d_in[26];
    const float* l2BA_as = (const float*)d_in[27];
    const float* l2BA_ad = (const float*)d_in[28];
    const float* l2BA_b  = (const float*)d_in[29];

    const int N = NNODES, E = NEDGES;

    // ---- workspace carve (4-byte elements, 64-element aligned) ----
    size_t o = 0;
    auto alloc = [&](size_t n) { size_t r = o; o += (n + 63) & ~(size_t)63; return r; };
    size_t cntA = alloc(N), cntB = alloc(N);
    size_t roA = alloc(N + 1), roB = alloc(N + 1);
    size_t curA = alloc(N), curB = alloc(N);
    size_t ssA = alloc(E), ssB = alloc(E);
    size_t swA = alloc(E), swB = alloc(E);
    size_t ce8 = alloc(8);
    size_t part = alloc(128);
    size_t pHAB = alloc((size_t)N * 52);  // packed bf16 [N][104] as uints
    size_t pHBA = alloc((size_t)N * 52);
    size_t ad1B = alloc((size_t)N * 4), ad1A = alloc((size_t)N * 4);
    size_t hA1 = alloc((size_t)N * 100), hB1 = alloc((size_t)N * 100);
    size_t H2AB = alloc((size_t)N * 50);  // packed bf16 [N][100] as uints
    size_t H2BA = alloc((size_t)N * 50);
    size_t as2AB = alloc(N), as2BA = alloc(N);
    size_t ad2AB = alloc(N), ad2BA = alloc(N);
    (void)ws_size;

    float* wsf = (float*)d_ws;
    int*   wsi = (int*)d_ws;
    u32*   wsu = (u32*)d_ws;

    // zero edge-count histograms (cntA..cntB contiguous span)
    hipMemsetAsync(wsi + cntA, 0, sizeof(int) * (cntB + N - cntA), stream);

    ce_kernel<<<2, 128, 0, stream>>>(l1AB_We, l1AB_ae, l1BA_We, l1BA_ae, wsf + ce8);

    const int eb = (2 * E + 255) / 256;
    count_kernel<<<eb, 256, 0, stream>>>(ei_AB, ei_BA, E, wsi + cntA, wsi + cntB);
    scanA_kernel<<<dim3(SCAN_NBLK, 2), SCAN_T, 0, stream>>>(
        wsi + cntA, wsi + cntB, wsi + roA, wsi + roB, wsi + part, N);
    scanB_kernel<<<1, 128, 0, stream>>>(wsi + part, SCAN_NBLK);
    scanC_kernel<<<dim3(SCAN_NBLK, 2), SCAN_T, 0, stream>>>(
        wsi + cntA, wsi + cntB, wsi + roA, wsi + roB, wsi + curA, wsi + curB, wsi + part, N);
    fill_kernel<<<eb, 256, 0, stream>>>(ei_AB, ei_BA, w_AB, w_BA, E, wsi + curA, wsi + curB,
                                        wsi + ssA, wsi + ssB, wsf + swA, wsf + swB);

    const int gb = (N + 127) / 128;  // 391
    // layer-1 node transforms (src roles -> packed bf16 tables; dst roles -> a_dst only)
    {
        GemmArgs g0 = {x_A, l1AB_Ws, l1AB_as, (void*)(wsu + pHAB), nullptr};
        GemmArgs g1 = {x_B, l1AB_Wd, l1AB_ad, nullptr, wsf + ad1B};
        GemmArgs g2 = {x_B, l1BA_Ws, l1BA_as, (void*)(wsu + pHBA), nullptr};
        GemmArgs g3 = {x_A, l1BA_Wd, l1BA_ad, nullptr, wsf + ad1A};
        gemm_att_kernel<128, 4><<<dim3(gb, 4), 256, 0, stream>>>(g0, g1, g2, g3, N);
    }

    const int wb = (N + 3) / 4;  // wave per node, 4 waves/block
    {
        Gather4Args g0 = {wsi + roA, wsi + ssA, wsf + swA, (const u16*)(wsu + pHAB),
                          wsf + ad1B, wsf + ce8, l1AB_b, wsf + hB1};
        Gather4Args g1 = {wsi + roB, wsi + ssB, wsf + swB, (const u16*)(wsu + pHBA),
                          wsf + ad1A, wsf + ce8 + 4, l1BA_b, wsf + hA1};
        gather4_kernel<<<dim3(wb, 2), 256, 0, stream>>>(g0, g1, N);
    }

    // layer-2 node transforms (src roles -> packed bf16 H + as; dst roles -> ad only)
    {
        GemmArgs g0 = {wsf + hA1, l2AB_Ws, l2AB_as, (void*)(wsu + H2AB), wsf + as2AB};
        GemmArgs g1 = {wsf + hB1, l2AB_Wd, l2AB_ad, nullptr, wsf + ad2AB};
        GemmArgs g2 = {wsf + hB1, l2BA_Ws, l2BA_as, (void*)(wsu + H2BA), wsf + as2BA};
        GemmArgs g3 = {wsf + hA1, l2BA_Wd, l2BA_ad, nullptr, wsf + ad2BA};
        gemm_att_kernel<100, 1><<<dim3(gb, 4), 256, 0, stream>>>(g0, g1, g2, g3, N);
    }

    float* out = (float*)d_out;
    // oA = BA direction (dst in A) -> d_out[0..5M); oB = AB direction -> d_out[5M..10M)
    {
        Gather1Args g0 = {wsi + roA, wsi + ssA, (const u16*)(wsu + H2AB), wsf + as2AB,
                          wsf + ad2AB, l2AB_b, out + (size_t)N * 100};
        Gather1Args g1 = {wsi + roB, wsi + ssB, (const u16*)(wsu + H2BA), wsf + as2BA,
                          wsf + ad2BA, l2BA_b, out};
        gather1_kernel<<<dim3(wb, 2), 256, 0, stream>>>(g0, g1, N);
    }
}

// Round 3
// 1213.849 us; speedup vs baseline: 1.0011x; 1.0011x over previous
//
#include <hip/hip_runtime.h>

// HeteroGAT: 2-layer bipartite GAT (heads=4,ch=25 concat + edge feat; then heads=1,ch=100).
// R6: layer-1 gather HBM-bound -> packed bf16 src tables [N][104].
// R7: layer-2 src tables bf16 [N][100] (measured: only -27us; tables were cache-absorbed).
// R8: rocprof showed warm gemm_att = 346us with VALUBusy 1.67% -> latency-stalled on
//     per-lane row loads (64 distinct cache lines per wave load, 512B row stride).
//   -> stage X via LDS: coalesced 128x32 K-chunk tiles (8 lanes/line), double-buffered
//      [2][128][33] (+1 pad, conflict-free), loads issued before compute (T14).
//   -> c0 via readfirstlane so W addressing is wave-uniform -> scalar path.
//   Numerics bit-identical (same fma order). Predicted: gemm1 346->~60us, total ~1215->~780.

#define NNODES 50000
#define NEDGES 800000
#define SCAN_T 1024
#define SCAN_NBLK ((NNODES + SCAN_T - 1) / SCAN_T)  // 49

typedef unsigned short u16;
typedef unsigned int u32;

__device__ __forceinline__ float b2f(u16 u) {
    union { u32 i; float f; } x;
    x.i = ((u32)u) << 16;
    return x.f;
}
__device__ __forceinline__ u16 f2b(float f) {  // RN-even
    union { float f; u32 i; } x;
    x.f = f;
    u32 r = x.i + 0x7FFFu + ((x.i >> 16) & 1u);
    return (u16)(r >> 16);
}

// ---------------- ce[h] = sum_c We[h*25+c]*ae[h*25+c] (edge-attn constant) ----------------
__global__ void ce_kernel(const float* __restrict__ WeA, const float* __restrict__ aeA,
                          const float* __restrict__ WeB, const float* __restrict__ aeB,
                          float* __restrict__ ce /*[8]: 0..3=AB, 4..7=BA*/) {
    const float* We = blockIdx.x ? WeB : WeA;
    const float* ae = blockIdx.x ? aeB : aeA;
    __shared__ float s[4];
    int tid = threadIdx.x;
    if (tid < 4) s[tid] = 0.f;
    __syncthreads();
    if (tid < 100) atomicAdd(&s[tid / 25], We[tid] * ae[tid]);
    __syncthreads();
    if (tid < 4) ce[blockIdx.x * 4 + tid] = s[tid];
}

// ---------------- CSR build ----------------
__global__ void count_kernel(const int* __restrict__ eiA, const int* __restrict__ eiB,
                             int E, int* cntA, int* cntB) {
    int i = blockIdx.x * blockDim.x + threadIdx.x;
    if (i < E) atomicAdd(&cntA[eiA[E + i]], 1);
    else if (i < 2 * E) atomicAdd(&cntB[eiB[E + (i - E)]], 1);
}

__global__ __launch_bounds__(SCAN_T) void scanA_kernel(
    const int* __restrict__ cntA, const int* __restrict__ cntB,
    int* __restrict__ roA, int* __restrict__ roB, int* __restrict__ partial, int N) {
    const int dir = blockIdx.y;
    const int* cnt = dir ? cntB : cntA;
    int* ro = dir ? roB : roA;
    const int tid = threadIdx.x;
    const int i = blockIdx.x * SCAN_T + tid;
    __shared__ int sm[SCAN_T];
    sm[tid] = (i < N) ? cnt[i] : 0;
    __syncthreads();
    for (int off = 1; off < SCAN_T; off <<= 1) {
        int t = (tid >= off) ? sm[tid - off] : 0;
        __syncthreads();
        sm[tid] += t;
        __syncthreads();
    }
    if (i < N) ro[i + 1] = sm[tid];
    if (tid == SCAN_T - 1) partial[dir * 64 + blockIdx.x] = sm[tid];
}

__global__ void scanB_kernel(int* __restrict__ partial, int nblk) {
    __shared__ int sm[128];
    const int tid = threadIdx.x;
    sm[tid] = ((tid & 63) < nblk) ? partial[tid] : 0;
    __syncthreads();
    if (tid < 2) {
        int run = 0;
        for (int b = 0; b < nblk; ++b) {
            int t = sm[tid * 64 + b];
            sm[tid * 64 + b] = run;
            run += t;
        }
    }
    __syncthreads();
    partial[tid] = sm[tid];
}

__global__ __launch_bounds__(SCAN_T) void scanC_kernel(
    const int* __restrict__ cntA, const int* __restrict__ cntB,
    int* __restrict__ roA, int* __restrict__ roB,
    int* __restrict__ curA, int* __restrict__ curB,
    const int* __restrict__ partial, int N) {
    const int dir = blockIdx.y;
    const int* cnt = dir ? cntB : cntA;
    int* ro = dir ? roB : roA;
    int* cur = dir ? curB : curA;
    const int poff = partial[dir * 64 + blockIdx.x];
    const int i = blockIdx.x * SCAN_T + threadIdx.x;
    if (i < N) {
        int c = cnt[i];
        int r = ro[i + 1] + poff;
        ro[i + 1] = r;
        cur[i] = r - c;
        if (i == 0) ro[0] = 0;
    }
}

__global__ void fill_kernel(const int* __restrict__ eiA, const int* __restrict__ eiB,
                            const float* __restrict__ wA, const float* __restrict__ wB,
                            int E, int* curA, int* curB,
                            int* __restrict__ ssA, int* __restrict__ ssB,
                            float* __restrict__ swA, float* __restrict__ swB) {
    int i = blockIdx.x * blockDim.x + threadIdx.x;
    if (i < E) {
        int s = eiA[i], d = eiA[E + i];
        int pos = atomicAdd(&curA[d], 1);
        ssA[pos] = s; swA[pos] = wA[i];
    } else if (i < 2 * E) {
        int j = i - E;
        int s = eiB[j], d = eiB[E + j];
        int pos = atomicAdd(&curB[d], 1);
        ssB[pos] = s; swB[pos] = wB[j];
    }
}

// ---------------- GEMM [N,K]x[K,100] + fused att ----------------
// 128 nodes/block; lane owns nodes (lane, lane+64); wave w owns cols [25w,25w+25).
// R8: X staged via LDS in 32-wide K-chunks, double-buffered [2][128][33] (+1 pad).
//     256 threads load the 128x32 tile coalesced (8 lanes per 128B line); loads for
//     chunk c+1 issue before compute of chunk c (latency hides under 3200cyc VALU).
// W via wave-uniform loads (c0 readfirstlane -> scalar addressing).
// HEADS==4 src role (H!=null): epilogue packs bf16 [node][104] (100 h + 4 a_src).
// HEADS==4 dst role (H==null): att[N,4] fp32 only.
// HEADS==1 src role: packed bf16 H [node][100] + att[N] fp32; dst role: att[N] only.
struct GemmArgs {
    const float* X;
    const float* W;
    const float* a;
    void* H;
    float* att;
};

template <int K, int HEADS>
__global__ __launch_bounds__(256, 4) void gemm_att_kernel(
    GemmArgs g0, GemmArgs g1, GemmArgs g2, GemmArgs g3, int N) {
    const GemmArgs ga[4] = {g0, g1, g2, g3};
    const GemmArgs g = ga[blockIdx.y];
    // stage buffer [2][128][33] f32 = 33792B; epilogue areas (<=15104B) alias it after
    // the chunk loop's final barrier.
    constexpr int XS_STRIDE = 33;
    constexpr int XS_BUF = 128 * XS_STRIDE;  // floats per buffer
    constexpr int SMEM_BYTES = 2 * XS_BUF * 4;  // 33792
    __shared__ __align__(16) char smem[SMEM_BYTES];
    const int tid = threadIdx.x;
    const int lane = tid & 63;
    const int w = tid >> 6;
    const int node0 = blockIdx.x * 128;
    const int nA = node0 + lane;
    const int nB = node0 + 64 + lane;
    const bool vA = nA < N, vB = nB < N;

    const int c0 = __builtin_amdgcn_readfirstlane(25 * w);  // wave-uniform -> scalar
    const float* Wp = g.W + c0;

    float acc0[25], acc1[25];
#pragma unroll
    for (int j = 0; j < 25; ++j) { acc0[j] = 0.f; acc1[j] = 0.f; }

    float* Xs = (float*)smem;
    float4 rv[4];

    // coalesced tile load: slot s -> node n = s>>3, k-offset ko = (s&7)*4
    auto issue_loads = [&](int k0) {
#pragma unroll
        for (int r = 0; r < 4; ++r) {
            const int s = tid + r * 256;
            const int n = s >> 3;
            const int ko = (s & 7) * 4;
            int row = node0 + n;
            if (row >= N) row = N - 1;  // valid addr; values masked in epilogue
            const float* xp = g.X + (size_t)row * K + k0 + ko;
            if constexpr (K % 32 == 0) {
                rv[r] = *(const float4*)xp;
            } else {
                const int kb = k0 + ko;
                float4 v = make_float4(0.f, 0.f, 0.f, 0.f);
                if (kb + 3 < K) {
                    v = *(const float4*)xp;
                } else {
                    if (kb < K) v.x = xp[0];
                    if (kb + 1 < K) v.y = xp[1];
                    if (kb + 2 < K) v.z = xp[2];
                }
                rv[r] = v;
            }
        }
    };
    auto write_lds = [&](int buf) {
#pragma unroll
        for (int r = 0; r < 4; ++r) {
            const int s = tid + r * 256;
            const int n = s >> 3;
            const int ko = (s & 7) * 4;
            float* dst = Xs + buf * XS_BUF + n * XS_STRIDE + ko;
            dst[0] = rv[r].x;
            dst[1] = rv[r].y;
            dst[2] = rv[r].z;
            dst[3] = rv[r].w;
        }
    };

    constexpr int C = (K + 31) / 32;
    issue_loads(0);
    write_lds(0);
    __syncthreads();
    for (int c = 0; c < C; ++c) {
        const int k0 = c * 32;
        const int kc = (K - k0 < 32) ? (K - k0) : 32;
        if (c + 1 < C) issue_loads(k0 + 32);
        const float* x0p = Xs + (c & 1) * XS_BUF + lane * XS_STRIDE;
        const float* x1p = x0p + 64 * XS_STRIDE;
#pragma unroll 4
        for (int kk = 0; kk < kc; ++kk) {
            const float xs0 = x0p[kk];
            const float xs1 = x1p[kk];
            float wr[25];
#pragma unroll
            for (int j = 0; j < 25; ++j) wr[j] = Wp[(k0 + kk) * 100 + j];
#pragma unroll
            for (int j = 0; j < 25; ++j) {
                acc0[j] = fmaf(xs0, wr[j], acc0[j]);
                acc1[j] = fmaf(xs1, wr[j], acc1[j]);
            }
        }
        if (c + 1 < C) write_lds((c + 1) & 1);
        __syncthreads();  // stage visible; also fences last compute before epilogue
    }

    float ap0 = 0.f, ap1 = 0.f;
#pragma unroll
    for (int j = 0; j < 25; ++j) {
        const float av = g.a[c0 + j];
        ap0 = fmaf(acc0[j], av, ap0);
        ap1 = fmaf(acc1[j], av, ap1);
    }

    const int rem = N - node0;
    if (HEADS == 4) {
        if (g.H == nullptr) {  // dst role: a_dst only
            if (vA) g.att[(size_t)nA * 4 + w] = ap0;
            if (vB) g.att[(size_t)nB * 4 + w] = ap1;
        } else {               // src role: packed bf16 rows [104], LDS stride 106 (odd uints)
            u16* sh = (u16*)smem;
            u32* sh32 = (u32*)smem;
            // chunk A
#pragma unroll
            for (int j = 0; j < 25; ++j) sh[lane * 106 + c0 + j] = f2b(acc0[j]);
            sh[lane * 106 + 100 + w] = f2b(ap0);
            __syncthreads();
            {
                const int limA = ((rem < 64) ? rem : 64) * 52;
                u32* Hb = (u32*)g.H + (size_t)node0 * 52;
                for (int i = tid; i < 64 * 52; i += 256) {
                    if (i < limA) {
                        int nd = i / 52;
                        Hb[i] = sh32[nd * 53 + (i - nd * 52)];
                    }
                }
            }
            __syncthreads();
            // chunk B
#pragma unroll
            for (int j = 0; j < 25; ++j) sh[lane * 106 + c0 + j] = f2b(acc1[j]);
            sh[lane * 106 + 100 + w] = f2b(ap1);
            __syncthreads();
            {
                const int remB = rem - 64;
                const int limB = ((remB < 64) ? (remB < 0 ? 0 : remB) : 64) * 52;
                u32* Hb = (u32*)g.H + (size_t)(node0 + 64) * 52;
                for (int i = tid; i < 64 * 52; i += 256) {
                    if (i < limB) {
                        int nd = i / 52;
                        Hb[i] = sh32[nd * 53 + (i - nd * 52)];
                    }
                }
            }
        }
    } else {
        // HEADS==1: packed bf16 rows [100] (50 u32), LDS stride 102 u16 (51 u32, odd)
        u16* sh = (u16*)smem;
        u32* sh32 = (u32*)smem;
        float* attp = (float*)(smem + 64 * 102 * 2);
        attp[w * 128 + lane] = ap0;
        attp[w * 128 + 64 + lane] = ap1;
        if (g.H != nullptr) {
            // chunk A
#pragma unroll
            for (int j = 0; j < 25; ++j) sh[lane * 102 + c0 + j] = f2b(acc0[j]);
            __syncthreads();
            {
                const int limA = ((rem < 64) ? rem : 64) * 50;
                u32* Hb = (u32*)g.H + (size_t)node0 * 50;
                for (int i = tid; i < 64 * 50; i += 256) {
                    if (i < limA) {
                        int nd = i / 50;
                        Hb[i] = sh32[nd * 51 + (i - nd * 50)];
                    }
                }
                if (tid < 128 && node0 + tid < N)
                    g.att[node0 + tid] =
                        attp[tid] + attp[128 + tid] + attp[256 + tid] + attp[384 + tid];
            }
            __syncthreads();
            // chunk B
#pragma unroll
            for (int j = 0; j < 25; ++j) sh[lane * 102 + c0 + j] = f2b(acc1[j]);
            __syncthreads();
            {
                const int remB = rem - 64;
                const int limB = ((remB < 64) ? (remB < 0 ? 0 : remB) : 64) * 50;
                u32* Hb = (u32*)g.H + (size_t)(node0 + 64) * 50;
                for (int i = tid; i < 64 * 50; i += 256) {
                    if (i < limB) {
                        int nd = i / 50;
                        Hb[i] = sh32[nd * 51 + (i - nd * 50)];
                    }
                }
            }
        } else {
            __syncthreads();
            if (tid < 128 && node0 + tid < N)
                g.att[node0 + tid] =
                    attp[tid] + attp[128 + tid] + attp[256 + tid] + attp[384 + tid];
        }
    }
}

// ---------------- layer-1 gather: wave per dst node, packed bf16 src rows ----------------
struct Gather4Args {
    const int* ro;
    const int* ss;
    const float* sw;
    const u16* hp;     // [Ns][104] bf16: 0..99 h, 100..103 a_src
    const float* ad;   // [Nd,4] fp32
    const float* ce;   // [4]
    const float* bias; // [100]
    float* outp;       // [Nd,100]
};

__global__ __launch_bounds__(256) void gather4_kernel(Gather4Args ga0, Gather4Args ga1, int Nd) {
    const Gather4Args ga[2] = {ga0, ga1};
    const Gather4Args g = ga[blockIdx.y];
    int wid = (int)((blockIdx.x * blockDim.x + threadIdx.x) >> 6);
    if (wid >= Nd) return;
    const int n = __builtin_amdgcn_readfirstlane(wid);
    const int lane = threadIdx.x & 63;
    const int beg = g.ro[n], end = g.ro[n + 1];
    const int c0 = lane, c1 = 64 + lane;
    const bool has1 = (c1 < 100);
    const int h0 = c0 / 25;
    const int h1 = (c1 / 25) & 3;
    const float ce0 = g.ce[h0], ce1 = g.ce[h1];
    const float ad0 = g.ad[n * 4 + h0], ad1 = g.ad[n * 4 + h1];
    float acc0 = 0.f, acc1 = 0.f, d0 = 0.f, d1 = 0.f;
    int p = beg;
    for (; p + 1 < end; p += 2) {
        const int sa = g.ss[p], sb = g.ss[p + 1];
        const float wa = g.sw[p], wb = g.sw[p + 1];
        const u16* ra = g.hp + (size_t)sa * 104;
        const u16* rb = g.hp + (size_t)sb * 104;
        float la0 = b2f(ra[100 + h0]) + ad0 + wa * ce0;
        float la1 = b2f(ra[100 + h1]) + ad1 + wa * ce1;
        float lb0 = b2f(rb[100 + h0]) + ad0 + wb * ce0;
        float lb1 = b2f(rb[100 + h1]) + ad1 + wb * ce1;
        la0 = fmaxf(la0, 0.2f * la0); la1 = fmaxf(la1, 0.2f * la1);
        lb0 = fmaxf(lb0, 0.2f * lb0); lb1 = fmaxf(lb1, 0.2f * lb1);
        const float pa0 = __expf(la0), pa1 = __expf(la1);
        const float pb0 = __expf(lb0), pb1 = __expf(lb1);
        const float va0 = b2f(ra[c0]), vb0 = b2f(rb[c0]);
        const float va1 = has1 ? b2f(ra[c1]) : 0.f;
        const float vb1 = has1 ? b2f(rb[c1]) : 0.f;
        acc0 = fmaf(pa0, va0, acc0); acc0 = fmaf(pb0, vb0, acc0);
        acc1 = fmaf(pa1, va1, acc1); acc1 = fmaf(pb1, vb1, acc1);
        d0 += pa0 + pb0;
        d1 += pa1 + pb1;
    }
    if (p < end) {
        const int s = g.ss[p];
        const float ww = g.sw[p];
        const u16* ra = g.hp + (size_t)s * 104;
        float l0 = b2f(ra[100 + h0]) + ad0 + ww * ce0;
        float l1 = b2f(ra[100 + h1]) + ad1 + ww * ce1;
        l0 = fmaxf(l0, 0.2f * l0);
        l1 = fmaxf(l1, 0.2f * l1);
        const float p0 = __expf(l0);
        const float p1 = __expf(l1);
        acc0 = fmaf(p0, b2f(ra[c0]), acc0);
        acc1 = fmaf(p1, has1 ? b2f(ra[c1]) : 0.f, acc1);
        d0 += p0;
        d1 += p1;
    }
    float r0 = (end > beg) ? acc0 / d0 : 0.f;
    float r1 = (end > beg) ? acc1 / d1 : 0.f;
    r0 += g.bias[c0];
    r0 = (r0 > 0.f) ? r0 : (__expf(r0) - 1.f);  // elu
    g.outp[(size_t)n * 100 + c0] = r0;
    if (has1) {
        r1 += g.bias[c1];
        r1 = (r1 > 0.f) ? r1 : (__expf(r1) - 1.f);
        g.outp[(size_t)n * 100 + c1] = r1;
    }
}

// ---------------- layer-2 gather: wave per dst node, heads=1, ch=100, bf16 rows ----------------
struct Gather1Args {
    const int* ro;
    const int* ss;
    const u16* hp;     // [Ns][100] bf16
    const float* as_;  // [Ns] fp32
    const float* ad;   // [Nd] fp32
    const float* bias; // [100]
    float* outp;       // [Nd,100]
};

__global__ __launch_bounds__(256) void gather1_kernel(Gather1Args ga0, Gather1Args ga1, int Nd) {
    const Gather1Args ga[2] = {ga0, ga1};
    const Gather1Args g = ga[blockIdx.y];
    int wid = (int)((blockIdx.x * blockDim.x + threadIdx.x) >> 6);
    if (wid >= Nd) return;
    const int n = __builtin_amdgcn_readfirstlane(wid);
    const int lane = threadIdx.x & 63;
    const int beg = g.ro[n], end = g.ro[n + 1];
    const int c0 = lane, c1 = 64 + lane;
    const bool has1 = (c1 < 100);
    const float adn = g.ad[n];
    float acc0 = 0.f, acc1 = 0.f, d0 = 0.f;
    int p = beg;
    for (; p + 1 < end; p += 2) {
        const int sa = g.ss[p], sb = g.ss[p + 1];
        float la = g.as_[sa] + adn;
        float lb = g.as_[sb] + adn;
        la = fmaxf(la, 0.2f * la);
        lb = fmaxf(lb, 0.2f * lb);
        const float pa = __expf(la), pb = __expf(lb);
        const u16* hra = g.hp + (size_t)sa * 100;
        const u16* hrb = g.hp + (size_t)sb * 100;
        const float va0 = b2f(hra[c0]), vb0 = b2f(hrb[c0]);
        const float va1 = has1 ? b2f(hra[c1]) : 0.f;
        const float vb1 = has1 ? b2f(hrb[c1]) : 0.f;
        acc0 = fmaf(pa, va0, acc0); acc0 = fmaf(pb, vb0, acc0);
        acc1 = fmaf(pa, va1, acc1); acc1 = fmaf(pb, vb1, acc1);
        d0 += pa + pb;
    }
    if (p < end) {
        const int s = g.ss[p];
        float l = g.as_[s] + adn;
        l = fmaxf(l, 0.2f * l);
        const float pe = __expf(l);
        const u16* hrow = g.hp + (size_t)s * 100;
        acc0 = fmaf(pe, b2f(hrow[c0]), acc0);
        acc1 = fmaf(pe, has1 ? b2f(hrow[c1]) : 0.f, acc1);
        d0 += pe;
    }
    float r0 = (end > beg) ? acc0 / d0 : 0.f;
    float r1 = (end > beg) ? acc1 / d0 : 0.f;
    g.outp[(size_t)n * 100 + c0] = r0 + g.bias[c0];
    if (has1) g.outp[(size_t)n * 100 + c1] = r1 + g.bias[c1];
}

extern "C" void kernel_launch(void* const* d_in, const int* in_sizes, int n_in,
                              void* d_out, int out_size, void* d_ws, size_t ws_size,
                              hipStream_t stream) {
    const float* x_A   = (const float*)d_in[0];
    const float* x_B   = (const float*)d_in[1];
    const int*   ei_AB = (const int*)d_in[2];
    const int*   ei_BA = (const int*)d_in[3];
    const float* w_AB  = (const float*)d_in[4];
    const float* w_BA  = (const float*)d_in[5];
    const float* l1AB_Ws = (const float*)d_in[6];
    const float* l1AB_Wd = (const float*)d_in[7];
    const float* l1AB_as = (const float*)d_in[8];
    const float* l1AB_ad = (const float*)d_in[9];
    const float* l1AB_We = (const float*)d_in[10];
    const float* l1AB_ae = (const float*)d_in[11];
    const float* l1AB_b  = (const float*)d_in[12];
    const float* l2AB_Ws = (const float*)d_in[13];
    const float* l2AB_Wd = (const float*)d_in[14];
    const float* l2AB_as = (const float*)d_in[15];
    const float* l2AB_ad = (const float*)d_in[16];
    const float* l2AB_b  = (const float*)d_in[17];
    const float* l1BA_Ws = (const float*)d_in[18];
    const float* l1BA_Wd = (const float*)d_in[19];
    const float* l1BA_as = (const float*)d_in[20];
    const float* l1BA_ad = (const float*)d_in[21];
    const float* l1BA_We = (const float*)d_in[22];
    const float* l1BA_ae = (const float*)d_in[23];
    const float* l1BA_b  = (const float*)d_in[24];
    const float* l2BA_Ws = (const float*)d_in[25];
    const float* l2BA_Wd = (const float*)d_in[26];
    const float* l2BA_as = (const float*)d_in[27];
    const float* l2BA_ad = (const float*)d_in[28];
    const float* l2BA_b  = (const float*)d_in[29];

    const int N = NNODES, E = NEDGES;

    // ---- workspace carve (4-byte elements, 64-element aligned) ----
    size_t o = 0;
    auto alloc = [&](size_t n) { size_t r = o; o += (n + 63) & ~(size_t)63; return r; };
    size_t cntA = alloc(N), cntB = alloc(N);
    size_t roA = alloc(N + 1), roB = alloc(N + 1);
    size_t curA = alloc(N), curB = alloc(N);
    size_t ssA = alloc(E), ssB = alloc(E);
    size_t swA = alloc(E), swB = alloc(E);
    size_t ce8 = alloc(8);
    size_t part = alloc(128);
    size_t pHAB = alloc((size_t)N * 52);  // packed bf16 [N][104] as uints
    size_t pHBA = alloc((size_t)N * 52);
    size_t ad1B = alloc((size_t)N * 4), ad1A = alloc((size_t)N * 4);
    size_t hA1 = alloc((size_t)N * 100), hB1 = alloc((size_t)N * 100);
    size_t H2AB = alloc((size_t)N * 50);  // packed bf16 [N][100] as uints
    size_t H2BA = alloc((size_t)N * 50);
    size_t as2AB = alloc(N), as2BA = alloc(N);
    size_t ad2AB = alloc(N), ad2BA = alloc(N);
    (void)ws_size;

    float* wsf = (float*)d_ws;
    int*   wsi = (int*)d_ws;
    u32*   wsu = (u32*)d_ws;

    // zero edge-count histograms (cntA..cntB contiguous span)
    hipMemsetAsync(wsi + cntA, 0, sizeof(int) * (cntB + N - cntA), stream);

    ce_kernel<<<2, 128, 0, stream>>>(l1AB_We, l1AB_ae, l1BA_We, l1BA_ae, wsf + ce8);

    const int eb = (2 * E + 255) / 256;
    count_kernel<<<eb, 256, 0, stream>>>(ei_AB, ei_BA, E, wsi + cntA, wsi + cntB);
    scanA_kernel<<<dim3(SCAN_NBLK, 2), SCAN_T, 0, stream>>>(
        wsi + cntA, wsi + cntB, wsi + roA, wsi + roB, wsi + part, N);
    scanB_kernel<<<1, 128, 0, stream>>>(wsi + part, SCAN_NBLK);
    scanC_kernel<<<dim3(SCAN_NBLK, 2), SCAN_T, 0, stream>>>(
        wsi + cntA, wsi + cntB, wsi + roA, wsi + roB, wsi + curA, wsi + curB, wsi + part, N);
    fill_kernel<<<eb, 256, 0, stream>>>(ei_AB, ei_BA, w_AB, w_BA, E, wsi + curA, wsi + curB,
                                        wsi + ssA, wsi + ssB, wsf + swA, wsf + swB);

    const int gb = (N + 127) / 128;  // 391
    // layer-1 node transforms (src roles -> packed bf16 tables; dst roles -> a_dst only)
    {
        GemmArgs g0 = {x_A, l1AB_Ws, l1AB_as, (void*)(wsu + pHAB), nullptr};
        GemmArgs g1 = {x_B, l1AB_Wd, l1AB_ad, nullptr, wsf + ad1B};
        GemmArgs g2 = {x_B, l1BA_Ws, l1BA_as, (void*)(wsu + pHBA), nullptr};
        GemmArgs g3 = {x_A, l1BA_Wd, l1BA_ad, nullptr, wsf + ad1A};
        gemm_att_kernel<128, 4><<<dim3(gb, 4), 256, 0, stream>>>(g0, g1, g2, g3, N);
    }

    const int wb = (N + 3) / 4;  // wave per node, 4 waves/block
    {
        Gather4Args g0 = {wsi + roA, wsi + ssA, wsf + swA, (const u16*)(wsu + pHAB),
                          wsf + ad1B, wsf + ce8, l1AB_b, wsf + hB1};
        Gather4Args g1 = {wsi + roB, wsi + ssB, wsf + swB, (const u16*)(wsu + pHBA),
                          wsf + ad1A, wsf + ce8 + 4, l1BA_b, wsf + hA1};
        gather4_kernel<<<dim3(wb, 2), 256, 0, stream>>>(g0, g1, N);
    }

    // layer-2 node transforms (src roles -> packed bf16 H + as; dst roles -> ad only)
    {
        GemmArgs g0 = {wsf + hA1, l2AB_Ws, l2AB_as, (void*)(wsu + H2AB), wsf + as2AB};
        GemmArgs g1 = {wsf + hB1, l2AB_Wd, l2AB_ad, nullptr, wsf + ad2AB};
        GemmArgs g2 = {wsf + hB1, l2BA_Ws, l2BA_as, (void*)(wsu + H2BA), wsf + as2BA};
        GemmArgs g3 = {wsf + hA1, l2BA_Wd, l2BA_ad, nullptr, wsf + ad2BA};
        gemm_att_kernel<100, 1><<<dim3(gb, 4), 256, 0, stream>>>(g0, g1, g2, g3, N);
    }

    float* out = (float*)d_out;
    // oA = BA direction (dst in A) -> d_out[0..5M); oB = AB direction -> d_out[5M..10M)
    {
        Gather1Args g0 = {wsi + roA, wsi + ssA, (const u16*)(wsu + H2AB), wsf + as2AB,
                          wsf + ad2AB, l2AB_b, out + (size_t)N * 100};
        Gather1Args g1 = {wsi + roB, wsi + ssB, (const u16*)(wsu + H2BA), wsf + as2BA,
                          wsf + ad2BA, l2BA_b, out};
        gather1_kernel<<<dim3(wb, 2), 256, 0, stream>>>(g0, g1, N);
    }
}

// Round 4
// 991.398 us; speedup vs baseline: 1.2258x; 1.2244x over previous
//
#include <hip/hip_runtime.h>

// HeteroGAT: 2-layer bipartite GAT (heads=4,ch=25 concat + edge feat; then heads=1,ch=100).
// R6: layer-1 gather HBM-bound -> packed bf16 src tables [N][104].
// R7: layer-2 src tables bf16 [N][100] (-27us only; tables were cache-absorbed).
// R8: X staged via LDS (gemm 346 -> ~270us; W-load VMEM stream remained).
// R9: rocprof budget: gemms still ~450-520us combined, VALU-idle on 3200 W vector
//     loads/wave (SGPR=32 proves no s_load promotion).
//   -> stage W per 32-chunk in LDS, double-buffered, wave-sliced [4][32][28]
//      (112B stride -> 16B-aligned 25-float slices, broadcast ds_read_b128).
//   -> inner loop: 9 LDS reads + 50 FMA per k-step, VALU-bound.
//   LDS 62.5KB -> 2 blocks/CU. Numerics bit-identical. Predict gemms ~60-90us each.

#define NNODES 50000
#define NEDGES 800000
#define SCAN_T 1024
#define SCAN_NBLK ((NNODES + SCAN_T - 1) / SCAN_T)  // 49

typedef unsigned short u16;
typedef unsigned int u32;

__device__ __forceinline__ float b2f(u16 u) {
    union { u32 i; float f; } x;
    x.i = ((u32)u) << 16;
    return x.f;
}
__device__ __forceinline__ u16 f2b(float f) {  // RN-even
    union { float f; u32 i; } x;
    x.f = f;
    u32 r = x.i + 0x7FFFu + ((x.i >> 16) & 1u);
    return (u16)(r >> 16);
}

// ---------------- ce[h] = sum_c We[h*25+c]*ae[h*25+c] (edge-attn constant) ----------------
__global__ void ce_kernel(const float* __restrict__ WeA, const float* __restrict__ aeA,
                          const float* __restrict__ WeB, const float* __restrict__ aeB,
                          float* __restrict__ ce /*[8]: 0..3=AB, 4..7=BA*/) {
    const float* We = blockIdx.x ? WeB : WeA;
    const float* ae = blockIdx.x ? aeB : aeA;
    __shared__ float s[4];
    int tid = threadIdx.x;
    if (tid < 4) s[tid] = 0.f;
    __syncthreads();
    if (tid < 100) atomicAdd(&s[tid / 25], We[tid] * ae[tid]);
    __syncthreads();
    if (tid < 4) ce[blockIdx.x * 4 + tid] = s[tid];
}

// ---------------- CSR build ----------------
__global__ void count_kernel(const int* __restrict__ eiA, const int* __restrict__ eiB,
                             int E, int* cntA, int* cntB) {
    int i = blockIdx.x * blockDim.x + threadIdx.x;
    if (i < E) atomicAdd(&cntA[eiA[E + i]], 1);
    else if (i < 2 * E) atomicAdd(&cntB[eiB[E + (i - E)]], 1);
}

__global__ __launch_bounds__(SCAN_T) void scanA_kernel(
    const int* __restrict__ cntA, const int* __restrict__ cntB,
    int* __restrict__ roA, int* __restrict__ roB, int* __restrict__ partial, int N) {
    const int dir = blockIdx.y;
    const int* cnt = dir ? cntB : cntA;
    int* ro = dir ? roB : roA;
    const int tid = threadIdx.x;
    const int i = blockIdx.x * SCAN_T + tid;
    __shared__ int sm[SCAN_T];
    sm[tid] = (i < N) ? cnt[i] : 0;
    __syncthreads();
    for (int off = 1; off < SCAN_T; off <<= 1) {
        int t = (tid >= off) ? sm[tid - off] : 0;
        __syncthreads();
        sm[tid] += t;
        __syncthreads();
    }
    if (i < N) ro[i + 1] = sm[tid];
    if (tid == SCAN_T - 1) partial[dir * 64 + blockIdx.x] = sm[tid];
}

__global__ void scanB_kernel(int* __restrict__ partial, int nblk) {
    __shared__ int sm[128];
    const int tid = threadIdx.x;
    sm[tid] = ((tid & 63) < nblk) ? partial[tid] : 0;
    __syncthreads();
    if (tid < 2) {
        int run = 0;
        for (int b = 0; b < nblk; ++b) {
            int t = sm[tid * 64 + b];
            sm[tid * 64 + b] = run;
            run += t;
        }
    }
    __syncthreads();
    partial[tid] = sm[tid];
}

__global__ __launch_bounds__(SCAN_T) void scanC_kernel(
    const int* __restrict__ cntA, const int* __restrict__ cntB,
    int* __restrict__ roA, int* __restrict__ roB,
    int* __restrict__ curA, int* __restrict__ curB,
    const int* __restrict__ partial, int N) {
    const int dir = blockIdx.y;
    const int* cnt = dir ? cntB : cntA;
    int* ro = dir ? roB : roA;
    int* cur = dir ? curB : curA;
    const int poff = partial[dir * 64 + blockIdx.x];
    const int i = blockIdx.x * SCAN_T + threadIdx.x;
    if (i < N) {
        int c = cnt[i];
        int r = ro[i + 1] + poff;
        ro[i + 1] = r;
        cur[i] = r - c;
        if (i == 0) ro[0] = 0;
    }
}

__global__ void fill_kernel(const int* __restrict__ eiA, const int* __restrict__ eiB,
                            const float* __restrict__ wA, const float* __restrict__ wB,
                            int E, int* curA, int* curB,
                            int* __restrict__ ssA, int* __restrict__ ssB,
                            float* __restrict__ swA, float* __restrict__ swB) {
    int i = blockIdx.x * blockDim.x + threadIdx.x;
    if (i < E) {
        int s = eiA[i], d = eiA[E + i];
        int pos = atomicAdd(&curA[d], 1);
        ssA[pos] = s; swA[pos] = wA[i];
    } else if (i < 2 * E) {
        int j = i - E;
        int s = eiB[j], d = eiB[E + j];
        int pos = atomicAdd(&curB[d], 1);
        ssB[pos] = s; swB[pos] = wB[j];
    }
}

// ---------------- GEMM [N,K]x[K,100] + fused att ----------------
// 128 nodes/block; lane owns nodes (lane, lane+64); wave w owns cols [25w,25w+25).
// R8/R9: BOTH operands staged via LDS per 32-wide K-chunk, double-buffered:
//   X [2][128][33] f32 (+1 pad, conflict-free per-lane reads)
//   W [2][4][32][28] f32 wave-sliced (16B-aligned 25-float slices, broadcast reads)
// Prefetch (global->reg) issued before compute; reg->LDS after; 1 barrier/chunk.
// HEADS==4 src role (H!=null): epilogue packs bf16 [node][104] (100 h + 4 a_src).
// HEADS==4 dst role (H==null): att[N,4] fp32 only.
// HEADS==1 src role: packed bf16 H [node][100] + att[N] fp32; dst role: att[N] only.
struct GemmArgs {
    const float* X;
    const float* W;
    const float* a;
    void* H;
    float* att;
};

template <int K, int HEADS>
__global__ __launch_bounds__(256, 2) void gemm_att_kernel(
    GemmArgs g0, GemmArgs g1, GemmArgs g2, GemmArgs g3, int N) {
    const GemmArgs ga[4] = {g0, g1, g2, g3};
    const GemmArgs g = ga[blockIdx.y];
    constexpr int XS_STRIDE = 33;
    constexpr int XS_BUF = 128 * XS_STRIDE;     // 4224 floats per buffer
    constexpr int WS_STRIDE = 28;               // 112B rows -> 16B aligned slices
    constexpr int WS_WAVE = 32 * WS_STRIDE;     // 896 floats per wave slice
    constexpr int WS_BUF = 4 * WS_WAVE;         // 3584 floats per buffer
    constexpr int SMEM_BYTES = (2 * XS_BUF + 2 * WS_BUF) * 4;  // 62464
    __shared__ __align__(16) char smem[SMEM_BYTES];
    const int tid = threadIdx.x;
    const int lane = tid & 63;
    const int w = tid >> 6;
    const int node0 = blockIdx.x * 128;
    const int nA = node0 + lane;
    const int nB = node0 + 64 + lane;
    const bool vA = nA < N, vB = nB < N;

    const int c0 = __builtin_amdgcn_readfirstlane(25 * w);  // wave-uniform

    float acc0[25], acc1[25];
#pragma unroll
    for (int j = 0; j < 25; ++j) { acc0[j] = 0.f; acc1[j] = 0.f; }

    float* Xs = (float*)smem;
    float* Wsh = (float*)smem + 2 * XS_BUF;
    float4 rv[4];
    float wv[13];

    // X tile load: slot s -> node n = s>>3, k-offset ko = (s&7)*4 (8 lanes per 128B line)
    auto issue_x = [&](int k0) {
#pragma unroll
        for (int r = 0; r < 4; ++r) {
            const int s = tid + r * 256;
            const int n = s >> 3;
            const int ko = (s & 7) * 4;
            int row = node0 + n;
            if (row >= N) row = N - 1;  // valid addr; values masked in epilogue
            const float* xp = g.X + (size_t)row * K + k0 + ko;
            if constexpr (K % 32 == 0) {
                rv[r] = *(const float4*)xp;
            } else {
                const int kb = k0 + ko;
                float4 v = make_float4(0.f, 0.f, 0.f, 0.f);
                if (kb + 3 < K) {
                    v = *(const float4*)xp;
                } else {
                    if (kb < K) v.x = xp[0];
                    if (kb + 1 < K) v.y = xp[1];
                    if (kb + 2 < K) v.z = xp[2];
                }
                rv[r] = v;
            }
        }
    };
    auto write_x = [&](int buf) {
#pragma unroll
        for (int r = 0; r < 4; ++r) {
            const int s = tid + r * 256;
            const int n = s >> 3;
            const int ko = (s & 7) * 4;
            float* dst = Xs + buf * XS_BUF + n * XS_STRIDE + ko;
            dst[0] = rv[r].x;
            dst[1] = rv[r].y;
            dst[2] = rv[r].z;
            dst[3] = rv[r].w;
        }
    };
    // W tile load: 32x100 rows (kc rows valid), contiguous global reads
    auto issue_w = [&](int k0, int kc) {
        const int lim = kc * 100;
#pragma unroll
        for (int r = 0; r < 13; ++r) {
            const int e = tid + r * 256;
            wv[r] = (e < lim) ? g.W[(size_t)k0 * 100 + e] : 0.f;
        }
    };
    auto write_w = [&](int buf, int kc) {
        const int lim = kc * 100;
#pragma unroll
        for (int r = 0; r < 13; ++r) {
            const int e = tid + r * 256;
            if (e < lim) {
                const int k = e / 100;
                const int j = e - k * 100;
                const int hd = j / 25;
                const int jj = j - hd * 25;
                Wsh[buf * WS_BUF + hd * WS_WAVE + k * WS_STRIDE + jj] = wv[r];
            }
        }
    };

    constexpr int C = (K + 31) / 32;
    {
        const int kc0 = (K < 32) ? K : 32;
        issue_x(0);
        issue_w(0, kc0);
        write_x(0);
        write_w(0, kc0);
    }
    __syncthreads();
    for (int c = 0; c < C; ++c) {
        const int k0 = c * 32;
        const int kc = (K - k0 < 32) ? (K - k0) : 32;
        const int kcn = (K - k0 - 32 < 32) ? (K - k0 - 32) : 32;
        if (c + 1 < C) {
            issue_x(k0 + 32);
            issue_w(k0 + 32, kcn);
        }
        const float* x0p = Xs + (c & 1) * XS_BUF + lane * XS_STRIDE;
        const float* x1p = x0p + 64 * XS_STRIDE;
        const float* wp = Wsh + (c & 1) * WS_BUF + w * WS_WAVE;
#pragma unroll 4
        for (int kk = 0; kk < kc; ++kk) {
            const float xs0 = x0p[kk];
            const float xs1 = x1p[kk];
            float wr[25];
#pragma unroll
            for (int j = 0; j < 25; ++j) wr[j] = wp[kk * WS_STRIDE + j];
#pragma unroll
            for (int j = 0; j < 25; ++j) {
                acc0[j] = fmaf(xs0, wr[j], acc0[j]);
                acc1[j] = fmaf(xs1, wr[j], acc1[j]);
            }
        }
        if (c + 1 < C) {
            __syncthreads();  // all waves done reading buf (c+1)&1 before overwrite
            write_x((c + 1) & 1);
            write_w((c + 1) & 1, kcn);
        }
        __syncthreads();
    }

    float ap0 = 0.f, ap1 = 0.f;
#pragma unroll
    for (int j = 0; j < 25; ++j) {
        const float av = g.a[c0 + j];
        ap0 = fmaf(acc0[j], av, ap0);
        ap1 = fmaf(acc1[j], av, ap1);
    }

    const int rem = N - node0;
    if (HEADS == 4) {
        if (g.H == nullptr) {  // dst role: a_dst only
            if (vA) g.att[(size_t)nA * 4 + w] = ap0;
            if (vB) g.att[(size_t)nB * 4 + w] = ap1;
        } else {               // src role: packed bf16 rows [104], LDS stride 106 (odd uints)
            u16* sh = (u16*)smem;
            u32* sh32 = (u32*)smem;
            // chunk A
#pragma unroll
            for (int j = 0; j < 25; ++j) sh[lane * 106 + c0 + j] = f2b(acc0[j]);
            sh[lane * 106 + 100 + w] = f2b(ap0);
            __syncthreads();
            {
                const int limA = ((rem < 64) ? rem : 64) * 52;
                u32* Hb = (u32*)g.H + (size_t)node0 * 52;
                for (int i = tid; i < 64 * 52; i += 256) {
                    if (i < limA) {
                        int nd = i / 52;
                        Hb[i] = sh32[nd * 53 + (i - nd * 52)];
                    }
                }
            }
            __syncthreads();
            // chunk B
#pragma unroll
            for (int j = 0; j < 25; ++j) sh[lane * 106 + c0 + j] = f2b(acc1[j]);
            sh[lane * 106 + 100 + w] = f2b(ap1);
            __syncthreads();
            {
                const int remB = rem - 64;
                const int limB = ((remB < 64) ? (remB < 0 ? 0 : remB) : 64) * 52;
                u32* Hb = (u32*)g.H + (size_t)(node0 + 64) * 52;
                for (int i = tid; i < 64 * 52; i += 256) {
                    if (i < limB) {
                        int nd = i / 52;
                        Hb[i] = sh32[nd * 53 + (i - nd * 52)];
                    }
                }
            }
        }
    } else {
        // HEADS==1: packed bf16 rows [100] (50 u32), LDS stride 102 u16 (51 u32, odd)
        u16* sh = (u16*)smem;
        u32* sh32 = (u32*)smem;
        float* attp = (float*)(smem + 64 * 102 * 2);
        attp[w * 128 + lane] = ap0;
        attp[w * 128 + 64 + lane] = ap1;
        if (g.H != nullptr) {
            // chunk A
#pragma unroll
            for (int j = 0; j < 25; ++j) sh[lane * 102 + c0 + j] = f2b(acc0[j]);
            __syncthreads();
            {
                const int limA = ((rem < 64) ? rem : 64) * 50;
                u32* Hb = (u32*)g.H + (size_t)node0 * 50;
                for (int i = tid; i < 64 * 50; i += 256) {
                    if (i < limA) {
                        int nd = i / 50;
                        Hb[i] = sh32[nd * 51 + (i - nd * 50)];
                    }
                }
                if (tid < 128 && node0 + tid < N)
                    g.att[node0 + tid] =
                        attp[tid] + attp[128 + tid] + attp[256 + tid] + attp[384 + tid];
            }
            __syncthreads();
            // chunk B
#pragma unroll
            for (int j = 0; j < 25; ++j) sh[lane * 102 + c0 + j] = f2b(acc1[j]);
            __syncthreads();
            {
                const int remB = rem - 64;
                const int limB = ((remB < 64) ? (remB < 0 ? 0 : remB) : 64) * 50;
                u32* Hb = (u32*)g.H + (size_t)(node0 + 64) * 50;
                for (int i = tid; i < 64 * 50; i += 256) {
                    if (i < limB) {
                        int nd = i / 50;
                        Hb[i] = sh32[nd * 51 + (i - nd * 50)];
                    }
                }
            }
        } else {
            __syncthreads();
            if (tid < 128 && node0 + tid < N)
                g.att[node0 + tid] =
                    attp[tid] + attp[128 + tid] + attp[256 + tid] + attp[384 + tid];
        }
    }
}

// ---------------- layer-1 gather: wave per dst node, packed bf16 src rows ----------------
struct Gather4Args {
    const int* ro;
    const int* ss;
    const float* sw;
    const u16* hp;     // [Ns][104] bf16: 0..99 h, 100..103 a_src
    const float* ad;   // [Nd,4] fp32
    const float* ce;   // [4]
    const float* bias; // [100]
    float* outp;       // [Nd,100]
};

__global__ __launch_bounds__(256) void gather4_kernel(Gather4Args ga0, Gather4Args ga1, int Nd) {
    const Gather4Args ga[2] = {ga0, ga1};
    const Gather4Args g = ga[blockIdx.y];
    int wid = (int)((blockIdx.x * blockDim.x + threadIdx.x) >> 6);
    if (wid >= Nd) return;
    const int n = __builtin_amdgcn_readfirstlane(wid);
    const int lane = threadIdx.x & 63;
    const int beg = g.ro[n], end = g.ro[n + 1];
    const int c0 = lane, c1 = 64 + lane;
    const bool has1 = (c1 < 100);
    const int h0 = c0 / 25;
    const int h1 = (c1 / 25) & 3;
    const float ce0 = g.ce[h0], ce1 = g.ce[h1];
    const float ad0 = g.ad[n * 4 + h0], ad1 = g.ad[n * 4 + h1];
    float acc0 = 0.f, acc1 = 0.f, d0 = 0.f, d1 = 0.f;
    int p = beg;
    for (; p + 1 < end; p += 2) {
        const int sa = g.ss[p], sb = g.ss[p + 1];
        const float wa = g.sw[p], wb = g.sw[p + 1];
        const u16* ra = g.hp + (size_t)sa * 104;
        const u16* rb = g.hp + (size_t)sb * 104;
        float la0 = b2f(ra[100 + h0]) + ad0 + wa * ce0;
        float la1 = b2f(ra[100 + h1]) + ad1 + wa * ce1;
        float lb0 = b2f(rb[100 + h0]) + ad0 + wb * ce0;
        float lb1 = b2f(rb[100 + h1]) + ad1 + wb * ce1;
        la0 = fmaxf(la0, 0.2f * la0); la1 = fmaxf(la1, 0.2f * la1);
        lb0 = fmaxf(lb0, 0.2f * lb0); lb1 = fmaxf(lb1, 0.2f * lb1);
        const float pa0 = __expf(la0), pa1 = __expf(la1);
        const float pb0 = __expf(lb0), pb1 = __expf(lb1);
        const float va0 = b2f(ra[c0]), vb0 = b2f(rb[c0]);
        const float va1 = has1 ? b2f(ra[c1]) : 0.f;
        const float vb1 = has1 ? b2f(rb[c1]) : 0.f;
        acc0 = fmaf(pa0, va0, acc0); acc0 = fmaf(pb0, vb0, acc0);
        acc1 = fmaf(pa1, va1, acc1); acc1 = fmaf(pb1, vb1, acc1);
        d0 += pa0 + pb0;
        d1 += pa1 + pb1;
    }
    if (p < end) {
        const int s = g.ss[p];
        const float ww = g.sw[p];
        const u16* ra = g.hp + (size_t)s * 104;
        float l0 = b2f(ra[100 + h0]) + ad0 + ww * ce0;
        float l1 = b2f(ra[100 + h1]) + ad1 + ww * ce1;
        l0 = fmaxf(l0, 0.2f * l0);
        l1 = fmaxf(l1, 0.2f * l1);
        const float p0 = __expf(l0);
        const float p1 = __expf(l1);
        acc0 = fmaf(p0, b2f(ra[c0]), acc0);
        acc1 = fmaf(p1, has1 ? b2f(ra[c1]) : 0.f, acc1);
        d0 += p0;
        d1 += p1;
    }
    float r0 = (end > beg) ? acc0 / d0 : 0.f;
    float r1 = (end > beg) ? acc1 / d1 : 0.f;
    r0 += g.bias[c0];
    r0 = (r0 > 0.f) ? r0 : (__expf(r0) - 1.f);  // elu
    g.outp[(size_t)n * 100 + c0] = r0;
    if (has1) {
        r1 += g.bias[c1];
        r1 = (r1 > 0.f) ? r1 : (__expf(r1) - 1.f);
        g.outp[(size_t)n * 100 + c1] = r1;
    }
}

// ---------------- layer-2 gather: wave per dst node, heads=1, ch=100, bf16 rows ----------------
struct Gather1Args {
    const int* ro;
    const int* ss;
    const u16* hp;     // [Ns][100] bf16
    const float* as_;  // [Ns] fp32
    const float* ad;   // [Nd] fp32
    const float* bias; // [100]
    float* outp;       // [Nd,100]
};

__global__ __launch_bounds__(256) void gather1_kernel(Gather1Args ga0, Gather1Args ga1, int Nd) {
    const Gather1Args ga[2] = {ga0, ga1};
    const Gather1Args g = ga[blockIdx.y];
    int wid = (int)((blockIdx.x * blockDim.x + threadIdx.x) >> 6);
    if (wid >= Nd) return;
    const int n = __builtin_amdgcn_readfirstlane(wid);
    const int lane = threadIdx.x & 63;
    const int beg = g.ro[n], end = g.ro[n + 1];
    const int c0 = lane, c1 = 64 + lane;
    const bool has1 = (c1 < 100);
    const float adn = g.ad[n];
    float acc0 = 0.f, acc1 = 0.f, d0 = 0.f;
    int p = beg;
    for (; p + 1 < end; p += 2) {
        const int sa = g.ss[p], sb = g.ss[p + 1];
        float la = g.as_[sa] + adn;
        float lb = g.as_[sb] + adn;
        la = fmaxf(la, 0.2f * la);
        lb = fmaxf(lb, 0.2f * lb);
        const float pa = __expf(la), pb = __expf(lb);
        const u16* hra = g.hp + (size_t)sa * 100;
        const u16* hrb = g.hp + (size_t)sb * 100;
        const float va0 = b2f(hra[c0]), vb0 = b2f(hrb[c0]);
        const float va1 = has1 ? b2f(hra[c1]) : 0.f;
        const float vb1 = has1 ? b2f(hrb[c1]) : 0.f;
        acc0 = fmaf(pa, va0, acc0); acc0 = fmaf(pb, vb0, acc0);
        acc1 = fmaf(pa, va1, acc1); acc1 = fmaf(pb, vb1, acc1);
        d0 += pa + pb;
    }
    if (p < end) {
        const int s = g.ss[p];
        float l = g.as_[s] + adn;
        l = fmaxf(l, 0.2f * l);
        const float pe = __expf(l);
        const u16* hrow = g.hp + (size_t)s * 100;
        acc0 = fmaf(pe, b2f(hrow[c0]), acc0);
        acc1 = fmaf(pe, has1 ? b2f(hrow[c1]) : 0.f, acc1);
        d0 += pe;
    }
    float r0 = (end > beg) ? acc0 / d0 : 0.f;
    float r1 = (end > beg) ? acc1 / d0 : 0.f;
    g.outp[(size_t)n * 100 + c0] = r0 + g.bias[c0];
    if (has1) g.outp[(size_t)n * 100 + c1] = r1 + g.bias[c1];
}

extern "C" void kernel_launch(void* const* d_in, const int* in_sizes, int n_in,
                              void* d_out, int out_size, void* d_ws, size_t ws_size,
                              hipStream_t stream) {
    const float* x_A   = (const float*)d_in[0];
    const float* x_B   = (const float*)d_in[1];
    const int*   ei_AB = (const int*)d_in[2];
    const int*   ei_BA = (const int*)d_in[3];
    const float* w_AB  = (const float*)d_in[4];
    const float* w_BA  = (const float*)d_in[5];
    const float* l1AB_Ws = (const float*)d_in[6];
    const float* l1AB_Wd = (const float*)d_in[7];
    const float* l1AB_as = (const float*)d_in[8];
    const float* l1AB_ad = (const float*)d_in[9];
    const float* l1AB_We = (const float*)d_in[10];
    const float* l1AB_ae = (const float*)d_in[11];
    const float* l1AB_b  = (const float*)d_in[12];
    const float* l2AB_Ws = (const float*)d_in[13];
    const float* l2AB_Wd = (const float*)d_in[14];
    const float* l2AB_as = (const float*)d_in[15];
    const float* l2AB_ad = (const float*)d_in[16];
    const float* l2AB_b  = (const float*)d_in[17];
    const float* l1BA_Ws = (const float*)d_in[18];
    const float* l1BA_Wd = (const float*)d_in[19];
    const float* l1BA_as = (const float*)d_in[20];
    const float* l1BA_ad = (const float*)d_in[21];
    const float* l1BA_We = (const float*)d_in[22];
    const float* l1BA_ae = (const float*)d_in[23];
    const float* l1BA_b  = (const float*)d_in[24];
    const float* l2BA_Ws = (const float*)d_in[25];
    const float* l2BA_Wd = (const float*)d_in[26];
    const float* l2BA_as = (const float*)d_in[27];
    const float* l2BA_ad = (const float*)d_in[28];
    const float* l2BA_b  = (const float*)d_in[29];

    const int N = NNODES, E = NEDGES;

    // ---- workspace carve (4-byte elements, 64-element aligned) ----
    size_t o = 0;
    auto alloc = [&](size_t n) { size_t r = o; o += (n + 63) & ~(size_t)63; return r; };
    size_t cntA = alloc(N), cntB = alloc(N);
    size_t roA = alloc(N + 1), roB = alloc(N + 1);
    size_t curA = alloc(N), curB = alloc(N);
    size_t ssA = alloc(E), ssB = alloc(E);
    size_t swA = alloc(E), swB = alloc(E);
    size_t ce8 = alloc(8);
    size_t part = alloc(128);
    size_t pHAB = alloc((size_t)N * 52);  // packed bf16 [N][104] as uints
    size_t pHBA = alloc((size_t)N * 52);
    size_t ad1B = alloc((size_t)N * 4), ad1A = alloc((size_t)N * 4);
    size_t hA1 = alloc((size_t)N * 100), hB1 = alloc((size_t)N * 100);
    size_t H2AB = alloc((size_t)N * 50);  // packed bf16 [N][100] as uints
    size_t H2BA = alloc((size_t)N * 50);
    size_t as2AB = alloc(N), as2BA = alloc(N);
    size_t ad2AB = alloc(N), ad2BA = alloc(N);
    (void)ws_size;

    float* wsf = (float*)d_ws;
    int*   wsi = (int*)d_ws;
    u32*   wsu = (u32*)d_ws;

    // zero edge-count histograms (cntA..cntB contiguous span)
    hipMemsetAsync(wsi + cntA, 0, sizeof(int) * (cntB + N - cntA), stream);

    ce_kernel<<<2, 128, 0, stream>>>(l1AB_We, l1AB_ae, l1BA_We, l1BA_ae, wsf + ce8);

    const int eb = (2 * E + 255) / 256;
    count_kernel<<<eb, 256, 0, stream>>>(ei_AB, ei_BA, E, wsi + cntA, wsi + cntB);
    scanA_kernel<<<dim3(SCAN_NBLK, 2), SCAN_T, 0, stream>>>(
        wsi + cntA, wsi + cntB, wsi + roA, wsi + roB, wsi + part, N);
    scanB_kernel<<<1, 128, 0, stream>>>(wsi + part, SCAN_NBLK);
    scanC_kernel<<<dim3(SCAN_NBLK, 2), SCAN_T, 0, stream>>>(
        wsi + cntA, wsi + cntB, wsi + roA, wsi + roB, wsi + curA, wsi + curB, wsi + part, N);
    fill_kernel<<<eb, 256, 0, stream>>>(ei_AB, ei_BA, w_AB, w_BA, E, wsi + curA, wsi + curB,
                                        wsi + ssA, wsi + ssB, wsf + swA, wsf + swB);

    const int gb = (N + 127) / 128;  // 391
    // layer-1 node transforms (src roles -> packed bf16 tables; dst roles -> a_dst only)
    {
        GemmArgs g0 = {x_A, l1AB_Ws, l1AB_as, (void*)(wsu + pHAB), nullptr};
        GemmArgs g1 = {x_B, l1AB_Wd, l1AB_ad, nullptr, wsf + ad1B};
        GemmArgs g2 = {x_B, l1BA_Ws, l1BA_as, (void*)(wsu + pHBA), nullptr};
        GemmArgs g3 = {x_A, l1BA_Wd, l1BA_ad, nullptr, wsf + ad1A};
        gemm_att_kernel<128, 4><<<dim3(gb, 4), 256, 0, stream>>>(g0, g1, g2, g3, N);
    }

    const int wb = (N + 3) / 4;  // wave per node, 4 waves/block
    {
        Gather4Args g0 = {wsi + roA, wsi + ssA, wsf + swA, (const u16*)(wsu + pHAB),
                          wsf + ad1B, wsf + ce8, l1AB_b, wsf + hB1};
        Gather4Args g1 = {wsi + roB, wsi + ssB, wsf + swB, (const u16*)(wsu + pHBA),
                          wsf + ad1A, wsf + ce8 + 4, l1BA_b, wsf + hA1};
        gather4_kernel<<<dim3(wb, 2), 256, 0, stream>>>(g0, g1, N);
    }

    // layer-2 node transforms (src roles -> packed bf16 H + as; dst roles -> ad only)
    {
        GemmArgs g0 = {wsf + hA1, l2AB_Ws, l2AB_as, (void*)(wsu + H2AB), wsf + as2AB};
        GemmArgs g1 = {wsf + hB1, l2AB_Wd, l2AB_ad, nullptr, wsf + ad2AB};
        GemmArgs g2 = {wsf + hB1, l2BA_Ws, l2BA_as, (void*)(wsu + H2BA), wsf + as2BA};
        GemmArgs g3 = {wsf + hA1, l2BA_Wd, l2BA_ad, nullptr, wsf + ad2BA};
        gemm_att_kernel<100, 1><<<dim3(gb, 4), 256, 0, stream>>>(g0, g1, g2, g3, N);
    }

    float* out = (float*)d_out;
    // oA = BA direction (dst in A) -> d_out[0..5M); oB = AB direction -> d_out[5M..10M)
    {
        Gather1Args g0 = {wsi + roA, wsi + ssA, (const u16*)(wsu + H2AB), wsf + as2AB,
                          wsf + ad2AB, l2AB_b, out + (size_t)N * 100};
        Gather1Args g1 = {wsi + roB, wsi + ssB, (const u16*)(wsu + H2BA), wsf + as2BA,
                          wsf + ad2BA, l2BA_b, out};
        gather1_kernel<<<dim3(wb, 2), 256, 0, stream>>>(g0, g1, N);
    }
}